// Round 1
// baseline (117.784 us; speedup 1.0000x reference)
//
#include <hip/hip_runtime.h>
#include <math.h>

#define NN 8192
#define DD 256
#define CHUNK 2048
constexpr float ALPHA = 0.2f;

// ---------------- Kernel 1: Wh = X @ W (fp32) ----------------
// 64x64 output tile, BK=32, 256 threads, 4x4 micro-tile per thread.
__global__ __launch_bounds__(256) void k_gemm(const float* __restrict__ X,
                                              const float* __restrict__ W,
                                              float* __restrict__ Wh) {
    __shared__ float As[64][36];   // [m][k], +4 pad keeps float4 alignment & breaks bank stride
    __shared__ float Bs[32][68];   // [k][n], +4 pad
    const int tid = threadIdx.x;
    const int tx = tid & 15;       // n-group
    const int ty = tid >> 4;       // m-group
    const int bx = blockIdx.x & 3;         // D/64 = 4 col tiles
    const int by = blockIdx.x >> 2;        // row tile
    const int row0 = by * 64, col0 = bx * 64;
    float acc[4][4] = {};
    for (int k0 = 0; k0 < DD; k0 += 32) {
        // load A tile 64x32 (512 float4, 2 per thread)
        #pragma unroll
        for (int i = 0; i < 2; ++i) {
            int idx = tid + i * 256;
            int r = idx >> 3;           // 8 float4 per row
            int c4 = idx & 7;
            float4 v = *(const float4*)(X + (size_t)(row0 + r) * DD + k0 + c4 * 4);
            *(float4*)&As[r][c4 * 4] = v;
        }
        // load B tile 32x64 (512 float4, 2 per thread)
        #pragma unroll
        for (int i = 0; i < 2; ++i) {
            int idx = tid + i * 256;
            int r = idx >> 4;           // 16 float4 per row
            int c4 = idx & 15;
            float4 v = *(const float4*)(W + (size_t)(k0 + r) * DD + col0 + c4 * 4);
            *(float4*)&Bs[r][c4 * 4] = v;
        }
        __syncthreads();
        #pragma unroll
        for (int kk = 0; kk < 32; ++kk) {
            float4 b = *(const float4*)&Bs[kk][tx * 4];
            #pragma unroll
            for (int i = 0; i < 4; ++i) {
                float a = As[ty * 4 + i][kk];
                acc[i][0] = fmaf(a, b.x, acc[i][0]);
                acc[i][1] = fmaf(a, b.y, acc[i][1]);
                acc[i][2] = fmaf(a, b.z, acc[i][2]);
                acc[i][3] = fmaf(a, b.w, acc[i][3]);
            }
        }
        __syncthreads();
    }
    #pragma unroll
    for (int i = 0; i < 4; ++i) {
        float4 v = make_float4(acc[i][0], acc[i][1], acc[i][2], acc[i][3]);
        *(float4*)(Wh + (size_t)(row0 + ty * 4 + i) * DD + col0 + tx * 4) = v;
    }
}

// ---------------- Kernel 1b: f1 = Wh@a1, f2 = Wh@a2 ----------------
// one wave per row (64 lanes x float4 = 256 elems), 4 rows per block.
__global__ __launch_bounds__(256) void k_f12(const float* __restrict__ Wh,
                                             const float* __restrict__ a1,
                                             const float* __restrict__ a2,
                                             float* __restrict__ f1,
                                             float* __restrict__ f2) {
    const int wid = threadIdx.x >> 6;
    const int lane = threadIdx.x & 63;
    const int row = blockIdx.x * 4 + wid;
    float4 w  = *(const float4*)(Wh + (size_t)row * DD + lane * 4);
    float4 v1 = *(const float4*)(a1 + lane * 4);
    float4 v2 = *(const float4*)(a2 + lane * 4);
    float s1 = w.x * v1.x + w.y * v1.y + w.z * v1.z + w.w * v1.w;
    float s2 = w.x * v2.x + w.y * v2.y + w.z * v2.z + w.w * v2.w;
    #pragma unroll
    for (int o = 32; o; o >>= 1) {
        s1 += __shfl_down(s1, o);
        s2 += __shfl_down(s2, o);
    }
    if (lane == 0) { f1[row] = s1; f2[row] = s2; }
}

// ---------------- Kernel 2: sparse GAT softmax-aggregate ----------------
// One block (256 threads) per output row. Scan adj row in 2048-col chunks,
// compact edges into LDS, online softmax across chunks; thread t owns output
// dim d=t and accumulates sum_j att_ij * Wh[j][d].
__global__ __launch_bounds__(256) void k_gat(const float* __restrict__ adj,
                                             const float* __restrict__ Wh,
                                             const float* __restrict__ f1,
                                             const float* __restrict__ f2,
                                             float* __restrict__ out) {
    __shared__ int   s_j[CHUNK];
    __shared__ float s_e[CHUNK];
    __shared__ int   s_cnt;
    __shared__ float s_red[4];
    const int row = blockIdx.x;
    const int tid = threadIdx.x;
    const int lane = tid & 63, wid = tid >> 6;
    const float f1i = f1[row];
    float m = -INFINITY, ssum = 0.f, acc = 0.f;
    const float4* arow = (const float4*)(adj + (size_t)row * NN);
    for (int c0 = 0; c0 < NN; c0 += CHUNK) {
        if (tid == 0) s_cnt = 0;
        __syncthreads();
        float lmax = -INFINITY;
        #pragma unroll
        for (int i = 0; i < CHUNK / 1024; ++i) {
            int fidx = (c0 >> 2) + tid + i * 256;
            float4 a = arow[fidx];
            int jb = c0 + (tid + i * 256) * 4;
            float av[4] = {a.x, a.y, a.z, a.w};
            #pragma unroll
            for (int q = 0; q < 4; ++q) {
                if (av[q] > 0.f) {
                    int j = jb + q;
                    float e = f1i + f2[j];
                    e = e > 0.f ? e : ALPHA * e;         // leaky_relu
                    int slot = atomicAdd(&s_cnt, 1);
                    s_j[slot] = j;
                    s_e[slot] = e;
                    lmax = fmaxf(lmax, e);
                }
            }
        }
        // block max of this chunk's edge scores
        #pragma unroll
        for (int o = 32; o; o >>= 1) lmax = fmaxf(lmax, __shfl_down(lmax, o));
        if (lane == 0) s_red[wid] = lmax;
        __syncthreads();                 // pushes + cnt + s_red final
        const int cnt = s_cnt;
        if (cnt > 0) {
            float Mc = fmaxf(fmaxf(s_red[0], s_red[1]), fmaxf(s_red[2], s_red[3]));
            float mnew = fmaxf(m, Mc);
            float scale = __expf(m - mnew);   // m=-inf -> 0, zeroes empty acc/ssum
            acc *= scale; ssum *= scale; m = mnew;
            for (int k = 0; k < cnt; ++k) {
                float w = __expf(s_e[k] - m);
                ssum += w;
                acc = fmaf(w, Wh[(size_t)s_j[k] * DD + tid], acc);
            }
        }
        __syncthreads();                 // everyone done reading before next reset
    }
    float o = acc / ssum;                // every row has a self loop -> ssum > 0
    out[(size_t)row * DD + tid] = o > 0.f ? o : 0.f;
}

extern "C" void kernel_launch(void* const* d_in, const int* in_sizes, int n_in,
                              void* d_out, int out_size, void* d_ws, size_t ws_size,
                              hipStream_t stream) {
    const float* X   = (const float*)d_in[0];
    const float* adj = (const float*)d_in[1];
    // d_in[2] = cmt_weight (unused by SPGAT)
    const float* W   = (const float*)d_in[3];
    const float* a1  = (const float*)d_in[4];
    const float* a2  = (const float*)d_in[5];
    float* out = (float*)d_out;

    float* Wh = (float*)d_ws;                 // N*D fp32 = 8 MB
    float* f1 = Wh + (size_t)NN * DD;         // N fp32
    float* f2 = f1 + NN;                      // N fp32

    k_gemm<<<dim3((NN / 64) * (DD / 64)), 256, 0, stream>>>(X, W, Wh);
    k_f12<<<NN / 4, 256, 0, stream>>>(Wh, a1, a2, f1, f2);
    k_gat<<<NN, 256, 0, stream>>>(adj, Wh, f1, f2, out);
}